// Round 1
// baseline (681.114 us; speedup 1.0000x reference)
//
#include <hip/hip_runtime.h>

#define NA   32          // nsp*nmax
#define NL   7           // LMAX+1
#define PERL 528         // 32 diag + 496 upper per l
#define NF   3696        // 7*528
#define NQ   924         // NF/4 float4 groups
#define TOT_LDS 1568     // 32 * 49 floats staged per sample

__global__ __launch_bounds__(256) void ps_norm_kernel(
    const float* __restrict__ se0, const float* __restrict__ se1,
    const float* __restrict__ se2, const float* __restrict__ se3,
    const float* __restrict__ se4, const float* __restrict__ se5,
    const float* __restrict__ se6, float* __restrict__ out)
{
    __shared__ float lds[TOT_LDS];
    __shared__ float s_wsum[4];
    __shared__ float s_inv;

    const int j   = blockIdx.x;
    const int tid = threadIdx.x;

    // ---- stage sample j's se data into LDS (float4 coalesced) ----
    const float* srcs[NL] = {se0, se1, se2, se3, se4, se5, se6};
    #pragma unroll
    for (int l = 0; l < NL; ++l) {
        const int cnt  = NA * (2 * l + 1);
        const int cnt4 = cnt >> 2;                    // all cnt divisible by 4
        const float4* src = (const float4*)(srcs[l] + (size_t)j * cnt);
        float4* dst = (float4*)(lds + NA * l * l);    // offset = 32*l^2
        for (int i = tid; i < cnt4; i += 256) dst[i] = src[i];
    }
    __syncthreads();

    // 1/sqrt(2l+1)
    const float rs[NL] = {1.0f, 0.57735026919f, 0.44721359549f,
                          0.37796447301f, 0.33333333333f,
                          0.30151134457f, 0.27735009811f};
    const float SQRT2 = 1.41421356237f;

    float vals[16];
    float ssq = 0.0f;

    #pragma unroll
    for (int k = 0; k < 4; ++k) {
        const int q = tid + k * 256;
        if (q < NQ) {
            const int f0 = 4 * q;
            const int l  = f0 / PERL;        // group of 4 never straddles l
            const int m21 = 2 * l + 1;
            const float* base = lds + NA * l * l;
            #pragma unroll
            for (int e = 0; e < 4; ++e) {
                const int f = f0 + e;
                const int t = f - l * PERL;
                int a, b;
                float scale;
                if (t < NA) {                // diagonal part
                    a = t; b = t;
                    scale = rs[l];
                } else {                     // strict upper triangle, row-major
                    const int u = t - NA;    // u in [0,496)
                    // row a: S(a)=a*(63-a)/2 <= u < S(a+1)
                    int aa = (int)((63.0f - sqrtf(3969.0f - 8.0f * (float)u)) * 0.5f);
                    if (aa < 0) aa = 0;
                    if (aa > 30) aa = 30;
                    while (aa > 0 && (aa * (63 - aa)) / 2 > u) --aa;
                    while (aa < 30 && ((aa + 1) * (62 - aa)) / 2 <= u) ++aa;
                    a = aa;
                    b = a + 1 + (u - (a * (63 - a)) / 2);
                    scale = SQRT2 * rs[l];
                }
                const float* ra = base + a * m21;
                const float* rb = base + b * m21;
                float dot = 0.0f;
                for (int m = 0; m < m21; ++m) dot = fmaf(ra[m], rb[m], dot);
                const float v = dot * scale;
                vals[4 * k + e] = v;
                ssq += v * v;
            }
        }
    }

    // ---- block reduction of sum of squares ----
    #pragma unroll
    for (int off = 32; off >= 1; off >>= 1)
        ssq += __shfl_down(ssq, off, 64);
    const int wid = tid >> 6;
    if ((tid & 63) == 0) s_wsum[wid] = ssq;
    __syncthreads();
    if (tid == 0) {
        const float tot = s_wsum[0] + s_wsum[1] + s_wsum[2] + s_wsum[3];
        s_inv = 1.0f / fmaxf(sqrtf(tot), 1e-12f);
    }
    __syncthreads();
    const float inv = s_inv;

    // ---- normalized float4 stores ----
    float4* outp = (float4*)(out + (size_t)j * NF);
    #pragma unroll
    for (int k = 0; k < 4; ++k) {
        const int q = tid + k * 256;
        if (q < NQ) {
            float4 v4;
            v4.x = vals[4 * k + 0] * inv;
            v4.y = vals[4 * k + 1] * inv;
            v4.z = vals[4 * k + 2] * inv;
            v4.w = vals[4 * k + 3] * inv;
            outp[q] = v4;
        }
    }
}

extern "C" void kernel_launch(void* const* d_in, const int* in_sizes, int n_in,
                              void* d_out, int out_size, void* d_ws, size_t ws_size,
                              hipStream_t stream) {
    const float* se0 = (const float*)d_in[0];
    const float* se1 = (const float*)d_in[1];
    const float* se2 = (const float*)d_in[2];
    const float* se3 = (const float*)d_in[3];
    const float* se4 = (const float*)d_in[4];
    const float* se5 = (const float*)d_in[5];
    const float* se6 = (const float*)d_in[6];
    float* out = (float*)d_out;

    const int J = in_sizes[0] / NA;   // se_0 is (J, 32, 1)
    ps_norm_kernel<<<J, 256, 0, stream>>>(se0, se1, se2, se3, se4, se5, se6, out);
}

// Round 2
// 322.254 us; speedup vs baseline: 2.1136x; 2.1136x over previous
//
#include <hip/hip_runtime.h>

#define NL   7
#define NA   32
#define PERL 528
#define NF   3696
#define SQRT2 1.41421356237309515f

// transposed staging: T-block for l starts at dword offset 36*l*l, layout [m][36]
#define TSTRIDE 36
#define TSIZE   (TSTRIDE * 49)   // 1764 floats = 7056 B

__global__ __launch_bounds__(256) void ps_kernel(
    const float* __restrict__ se0, const float* __restrict__ se1,
    const float* __restrict__ se2, const float* __restrict__ se3,
    const float* __restrict__ se4, const float* __restrict__ se5,
    const float* __restrict__ se6, float* __restrict__ out)
{
    __shared__ float T[TSIZE];
    __shared__ float s_wsum[4];
    __shared__ float s_inv;

    const int j   = blockIdx.x;
    const int tid = threadIdx.x;

    const float* srcs[NL] = {se0, se1, se2, se3, se4, se5, se6};
    // prefix of per-l element counts (32*(2l+1)): 0,32,128,288,512,800,1152,1568
    const int P[NL] = {0, 32, 128, 288, 512, 800, 1152};
    const unsigned mulr[NL] = {65536u, 21846u, 13108u, 9363u, 7282u, 5958u, 5042u};
    // sigma_l = (2l+1)^(-1/4); product of two staged values carries 1/sqrt(2l+1)
    const float sig[NL] = {1.0f, 0.7598356857f, 0.6687403050f, 0.6147881530f,
                           0.5773502692f, 0.5491004042f, 0.5266403878f};

    // ---- phase 1: stage sample j into LDS, transposed [m][a], pre-scaled ----
    for (int g = tid; g < 392; g += 256) {          // 392 float4 groups = 1568 floats
        const int e0 = 4 * g;
        int l;
        if      (e0 >= 1152) l = 6;
        else if (e0 >=  800) l = 5;
        else if (e0 >=  512) l = 4;
        else if (e0 >=  288) l = 3;
        else if (e0 >=  128) l = 2;
        else if (e0 >=   32) l = 1;
        else                 l = 0;
        const int m21 = 2 * l + 1;
        const int eL  = e0 - P[l];
        int a = (int)(((unsigned)eL * mulr[l]) >> 16);
        int m = eL - a * m21;
        const float4 v = *(const float4*)(srcs[l] + (size_t)j * (NA * m21) + eL);
        const float s  = sig[l];
        float vv[4] = {v.x, v.y, v.z, v.w};
        const int base = TSTRIDE * l * l;
        #pragma unroll
        for (int i = 0; i < 4; ++i) {
            T[base + m * TSTRIDE + a] = vv[i] * s;
            if (++m == m21) { m = 0; ++a; }
        }
    }
    __syncthreads();

    // ---- phase 2: per-wave full 32x32 Gram, 4x4 register tiles ----
    // wave w: slot0 -> l = 6-w (m21 = 13,11,9,7), slot1 -> l = w (w<3: 1,3,5)
    const int wv   = tid >> 6;
    const int lane = tid & 63;
    const int ta   = lane >> 3;   // 0..7
    const int tb   = lane & 7;    // 0..7

    float acc[2][4][4];
    #pragma unroll
    for (int s = 0; s < 2; ++s)
        #pragma unroll
        for (int i = 0; i < 4; ++i)
            #pragma unroll
            for (int k = 0; k < 4; ++k) acc[s][i][k] = 0.0f;

    #pragma unroll
    for (int s = 0; s < 2; ++s) {
        if (s == 1 && wv >= 3) break;
        const int l   = (s == 0) ? (6 - wv) : wv;
        const int m21 = 2 * l + 1;
        const float* Tb = T + TSTRIDE * l * l;
        for (int m = 0; m < m21; ++m) {
            const float4 x = *(const float4*)(Tb + m * TSTRIDE + 4 * ta);
            const float4 y = *(const float4*)(Tb + m * TSTRIDE + 4 * tb);
            const float xs[4] = {x.x, x.y, x.z, x.w};
            const float ys[4] = {y.x, y.y, y.z, y.w};
            #pragma unroll
            for (int i = 0; i < 4; ++i)
                #pragma unroll
                for (int k = 0; k < 4; ++k)
                    acc[s][i][k] = fmaf(xs[i], ys[k], acc[s][i][k]);
        }
    }

    // ---- phase 3: ssq partial from registers (unused slots are zero) ----
    float ssq = 0.0f;
    #pragma unroll
    for (int s = 0; s < 2; ++s) {
        if (ta < tb) {
            float t16 = 0.0f;
            #pragma unroll
            for (int i = 0; i < 4; ++i)
                #pragma unroll
                for (int k = 0; k < 4; ++k) t16 += acc[s][i][k] * acc[s][i][k];
            ssq += 2.0f * t16;
        } else if (ta == tb) {
            #pragma unroll
            for (int i = 0; i < 4; ++i) {
                ssq += acc[s][i][i] * acc[s][i][i];
                #pragma unroll
                for (int k = i + 1; k < 4; ++k) ssq += 2.0f * acc[s][i][k] * acc[s][i][k];
            }
        }
    }

    #pragma unroll
    for (int off = 32; off >= 1; off >>= 1) ssq += __shfl_down(ssq, off, 64);
    if (lane == 0) s_wsum[wv] = ssq;
    __syncthreads();
    if (tid == 0) {
        const float tot = s_wsum[0] + s_wsum[1] + s_wsum[2] + s_wsum[3];
        s_inv = 1.0f / fmaxf(sqrtf(tot), 1e-12f);
    }
    __syncthreads();
    const float inv = s_inv;

    // ---- phase 4: normalized stores straight from registers ----
    float* op = out + (size_t)j * NF;
    #pragma unroll
    for (int s = 0; s < 2; ++s) {
        if (s == 1 && wv >= 3) break;
        const int l = (s == 0) ? (6 - wv) : wv;
        float* ol = op + PERL * l;
        const float si = SQRT2 * inv;
        if (ta == tb) {
            float4 d;
            d.x = acc[s][0][0] * inv; d.y = acc[s][1][1] * inv;
            d.z = acc[s][2][2] * inv; d.w = acc[s][3][3] * inv;
            *(float4*)(ol + 4 * ta) = d;
            #pragma unroll
            for (int i = 0; i < 3; ++i) {
                const int a  = 4 * ta + i;
                const int rb = 32 + a * (63 - a) / 2 - a - 1;   // add b to finish
                #pragma unroll
                for (int k = i + 1; k < 4; ++k)
                    ol[rb + 4 * ta + k] = acc[s][i][k] * si;
            }
        } else if (ta < tb) {
            #pragma unroll
            for (int i = 0; i < 4; ++i) {
                const int a  = 4 * ta + i;
                const int rb = 32 + a * (63 - a) / 2 - a - 1 + 4 * tb;
                #pragma unroll
                for (int k = 0; k < 4; ++k)
                    ol[rb + k] = acc[s][i][k] * si;
            }
        }
    }
}

extern "C" void kernel_launch(void* const* d_in, const int* in_sizes, int n_in,
                              void* d_out, int out_size, void* d_ws, size_t ws_size,
                              hipStream_t stream) {
    const float* se0 = (const float*)d_in[0];
    const float* se1 = (const float*)d_in[1];
    const float* se2 = (const float*)d_in[2];
    const float* se3 = (const float*)d_in[3];
    const float* se4 = (const float*)d_in[4];
    const float* se5 = (const float*)d_in[5];
    const float* se6 = (const float*)d_in[6];
    float* out = (float*)d_out;

    const int J = in_sizes[0] / NA;   // se_0 is (J, 32, 1)
    ps_kernel<<<J, 256, 0, stream>>>(se0, se1, se2, se3, se4, se5, se6, out);
}